// Round 5
// baseline (536.656 us; speedup 1.0000x reference)
//
#include <hip/hip_runtime.h>

// Problem constants (QLinear_17918603559229)
#define TOKENS 8192
#define IN_F   4096
#define OUT_F  4096
#define GK     IN_F
#define GN     OUT_F

#define BM 128
#define BN 128
#define BK 64

typedef __attribute__((ext_vector_type(8))) short bf16x8;
typedef __attribute__((ext_vector_type(4))) float f32x4;
typedef __attribute__((address_space(1))) void gvoid;
typedef __attribute__((address_space(3))) void lvoid;

static __device__ __forceinline__ unsigned short f32_to_bf16(float f) {
  union { float f; unsigned int u; } v; v.f = f;
  unsigned int u = v.u;
  return (unsigned short)((u + 0x7FFFu + ((u >> 16) & 1u)) >> 16);  // RNE
}

// ---------------- fused prep: cast x (f32->bf16) + build W (bf16) ----------------
// blocks [0, 16384): cast 8 elems/thread; blocks [16384, 32768): build 4 elems/thread
__global__ void prep_kernel(const float4* __restrict__ x, bf16x8* __restrict__ xb,
                            const float* __restrict__ a, const float* __restrict__ s,
                            unsigned short* __restrict__ wb) {
  const int bid = blockIdx.x;
  if (bid < 16384) {
    const int idx = bid * 256 + threadIdx.x;
    float4 v0 = x[idx * 2];
    float4 v1 = x[idx * 2 + 1];
    bf16x8 r;
    r[0] = (short)f32_to_bf16(v0.x); r[1] = (short)f32_to_bf16(v0.y);
    r[2] = (short)f32_to_bf16(v0.z); r[3] = (short)f32_to_bf16(v0.w);
    r[4] = (short)f32_to_bf16(v1.x); r[5] = (short)f32_to_bf16(v1.y);
    r[6] = (short)f32_to_bf16(v1.z); r[7] = (short)f32_to_bf16(v1.w);
    xb[idx] = r;
  } else {
    const int gid = (bid - 16384) * 256 + threadIdx.x;   // OUT_F * IN_F / 4 threads
    const int o = gid >> 10;
    const int i = (gid & 1023) << 2;                      // 4 consecutive i, same j-block
    const int ib = o >> 10, p = o & 1023;
    const int jb = i >> 10, q = i & 1023;
    float r0 = 0.f, r1 = 0.f, r2 = 0.f, r3 = 0.f;
#pragma unroll
    for (int k = 0; k < 4; ++k) {
      float ak = a[k * 16 + ib * 4 + jb];
      const float4 sv = *(const float4*)(s + (((size_t)(k * 1024 + p)) << 10) + q);
      r0 += ak * sv.x; r1 += ak * sv.y; r2 += ak * sv.z; r3 += ak * sv.w;
    }
    ushort4 w;
    w.x = f32_to_bf16(r0); w.y = f32_to_bf16(r1);
    w.z = f32_to_bf16(r2); w.w = f32_to_bf16(r3);
    *(ushort4*)(wb + ((size_t)o << 12) + i) = w;
  }
}

// ---------------- GEMM: C[M,N] = A[M,K] @ B[N,K]^T + bias, bf16 in / f32 out ----------------
// m97 2-barrier loop, 128x128 tile, BK=64 — but TWO waves (128 thr), each owning a
// 64x128 output slab (acc[4][8]).  Rationale (r4 counters): the 4-wave/64x64 variant is
// LDS-read-BW-bound (192 b128 wave-reads/CU/K-step ~= 232 B/cyc ~= 91% of 256 B/clk
// spec, MfmaUtil capped at 55%).  64x128 per wave = 42.7 FLOP/LDS-byte vs 32 —
// 25% fewer LDS reads per MFMA; at ~200 VGPR -> 2 waves/SIMD -> 4 blocks/CU: same
// 192 LDS reads/CU/K-step but 512 MFMAs (vs 384).  Cross-block slip preserved.
// Swizzle unchanged: LDS[row][g] = G[row][g ^ (row&7)], inverse-swizzle on global src.
__global__ __launch_bounds__(128, 2)
void gemm_bias_kernel(const unsigned short* __restrict__ A,
                      const unsigned short* __restrict__ B,
                      const float* __restrict__ bias,
                      float* __restrict__ C) {
  __shared__ unsigned short As[BM * BK];   // 16 KB
  __shared__ unsigned short Bs[BN * BK];   // 16 KB

  const int tid  = threadIdx.x;
  const int lane = tid & 63;
  const int wave = tid >> 6;               // 0..1
  const int m0 = blockIdx.y * BM;
  const int n0 = blockIdx.x * BN;
  const int wm = wave * 64;                // wave's A-row slab; both waves span all 128 cols

  f32x4 acc[4][8];
#pragma unroll
  for (int mi = 0; mi < 4; ++mi)
#pragma unroll
    for (int ni = 0; ni < 8; ++ni)
      acc[mi][ni] = (f32x4){0.f, 0.f, 0.f, 0.f};

  // staging map: pass p covers rows p*16 + (tid>>3); granule (tid&7), swizzled source
  const int srow = tid >> 3;               // 0..15
  const int sgr  = (tid & 7) ^ (srow & 7);
  const unsigned short* Ag = A + (size_t)(m0 + srow) * GK + sgr * 8;
  const unsigned short* Bg = B + (size_t)(n0 + srow) * GK + sgr * 8;
  unsigned short* Asd = As + tid * 8;      // lane-contiguous LDS dest
  unsigned short* Bsd = Bs + tid * 8;

  const int ln15 = lane & 15;
  const int quad = lane >> 4;
  const int sw   = lane & 7;               // == (frag row) & 7
  int rowA[4], rowB[8];
#pragma unroll
  for (int t = 0; t < 4; ++t)
    rowA[t] = (wm + t * 16 + ln15) * BK;
#pragma unroll
  for (int t = 0; t < 8; ++t)
    rowB[t] = (t * 16 + ln15) * BK;

  for (int k0 = 0; k0 < GK; k0 += BK) {
#pragma unroll
    for (int p = 0; p < 8; ++p) {
      __builtin_amdgcn_global_load_lds((const gvoid*)(Ag + (size_t)(p * 16) * GK + k0),
                                       (lvoid*)(Asd + p * 1024), 16, 0, 0);
      __builtin_amdgcn_global_load_lds((const gvoid*)(Bg + (size_t)(p * 16) * GK + k0),
                                       (lvoid*)(Bsd + p * 1024), 16, 0, 0);
    }
    __syncthreads();
#pragma unroll
    for (int half = 0; half < 2; ++half) {
      const int gk   = half * 4 + quad;          // source granule wanted (k = gk*8 + j)
      const int cofs = ((gk ^ sw) << 3);         // swizzled LDS column (elements)
      bf16x8 af[4], bfr[8];
#pragma unroll
      for (int t = 0; t < 4; ++t)
        af[t]  = *(const bf16x8*)(As + rowA[t] + cofs);
#pragma unroll
      for (int t = 0; t < 8; ++t)
        bfr[t] = *(const bf16x8*)(Bs + rowB[t] + cofs);
#pragma unroll
      for (int mi = 0; mi < 4; ++mi)
#pragma unroll
        for (int ni = 0; ni < 8; ++ni)
          acc[mi][ni] = __builtin_amdgcn_mfma_f32_16x16x32_bf16(af[mi], bfr[ni],
                                                                acc[mi][ni], 0, 0, 0);
    }
    __syncthreads();
  }

  // epilogue: C/D layout col = lane&15, row = quad*4 + reg  [m89/m91 verified]
#pragma unroll
  for (int ni = 0; ni < 8; ++ni) {
    const int col = n0 + ni * 16 + ln15;
    const float bv = bias[col];
#pragma unroll
    for (int mi = 0; mi < 4; ++mi) {
      const int rowb = m0 + wm + mi * 16 + quad * 4;
#pragma unroll
      for (int r = 0; r < 4; ++r)
        C[(size_t)(rowb + r) * GN + col] = acc[mi][ni][r] + bv;
    }
  }
}

// ---------------- naive fallback (only if ws too small) ----------------
__global__ void naive_kernel(const float* __restrict__ x, const float* __restrict__ a,
                             const float* __restrict__ s, const float* __restrict__ bias,
                             float* __restrict__ out) {
  long long idx = (long long)blockIdx.x * blockDim.x + threadIdx.x;
  if (idx >= (long long)TOKENS * OUT_F) return;
  int t = (int)(idx >> 12);
  int o = (int)(idx & 4095);
  int ib = o >> 10, p = o & 1023;
  float acc = bias[o];
  for (int jb = 0; jb < 4; ++jb) {
    float a0 = a[0  + ib * 4 + jb];
    float a1 = a[16 + ib * 4 + jb];
    float a2 = a[32 + ib * 4 + jb];
    float a3 = a[48 + ib * 4 + jb];
    const float* xr = x + (size_t)t * IN_F + jb * 1024;
    const float* s0 = s + (size_t)p * 1024;
    const float* s1 = s0 + 1048576;
    const float* s2 = s1 + 1048576;
    const float* s3 = s2 + 1048576;
    for (int q = 0; q < 1024; ++q) {
      float w = a0 * s0[q] + a1 * s1[q] + a2 * s2[q] + a3 * s3[q];
      acc += xr[q] * w;
    }
  }
  out[idx] = acc;
}

extern "C" void kernel_launch(void* const* d_in, const int* in_sizes, int n_in,
                              void* d_out, int out_size, void* d_ws, size_t ws_size,
                              hipStream_t stream) {
  const float* x    = (const float*)d_in[0];
  const float* a    = (const float*)d_in[1];
  const float* s    = (const float*)d_in[2];
  const float* bias = (const float*)d_in[3];
  float* out = (float*)d_out;

  const size_t xb_elems = (size_t)TOKENS * IN_F;          // 33.5M bf16 = 67 MB
  const size_t wb_elems = (size_t)OUT_F * IN_F;           // 16.7M bf16 = 33.5 MB
  const size_t need = (xb_elems + wb_elems) * sizeof(unsigned short);

  if (ws_size >= need) {
    unsigned short* Xb = (unsigned short*)d_ws;
    unsigned short* Wb = Xb + xb_elems;
    const int cast_blocks  = (int)(xb_elems / 8 / 256);   // 16384
    const int build_blocks = (int)(wb_elems / 4 / 256);   // 16384
    prep_kernel<<<cast_blocks + build_blocks, 256, 0, stream>>>(
        (const float4*)x, (bf16x8*)Xb, a, s, Wb);
    dim3 grid(GN / BN, TOKENS / BM);                      // (32, 64) = 2048 blocks
    gemm_bias_kernel<<<grid, 128, 0, stream>>>(Xb, Wb, bias, out);
  } else {
    long long total = (long long)TOKENS * OUT_F;
    naive_kernel<<<(int)((total + 255) / 256), 256, 0, stream>>>(x, a, s, bias, out);
  }
}

// Round 6
// 508.605 us; speedup vs baseline: 1.0552x; 1.0552x over previous
//
#include <hip/hip_runtime.h>

// Problem constants (QLinear_17918603559229)
#define TOKENS 8192
#define IN_F   4096
#define OUT_F  4096
#define GK     IN_F
#define GN     OUT_F

#define BM 128
#define BN 128
#define BK 64

typedef __attribute__((ext_vector_type(8))) short bf16x8;
typedef __attribute__((ext_vector_type(4))) float f32x4;
typedef __attribute__((address_space(1))) void gvoid;
typedef __attribute__((address_space(3))) void lvoid;

static __device__ __forceinline__ unsigned short f32_to_bf16(float f) {
  union { float f; unsigned int u; } v; v.f = f;
  unsigned int u = v.u;
  return (unsigned short)((u + 0x7FFFu + ((u >> 16) & 1u)) >> 16);  // RNE
}

// ---------------- fused prep: cast x (f32->bf16) + build W (bf16) ----------------
// blocks [0, 16384): cast 8 elems/thread; blocks [16384, 32768): build 4 elems/thread
__global__ void prep_kernel(const float4* __restrict__ x, bf16x8* __restrict__ xb,
                            const float* __restrict__ a, const float* __restrict__ s,
                            unsigned short* __restrict__ wb) {
  const int bid = blockIdx.x;
  if (bid < 16384) {
    const int idx = bid * 256 + threadIdx.x;
    float4 v0 = x[idx * 2];
    float4 v1 = x[idx * 2 + 1];
    bf16x8 r;
    r[0] = (short)f32_to_bf16(v0.x); r[1] = (short)f32_to_bf16(v0.y);
    r[2] = (short)f32_to_bf16(v0.z); r[3] = (short)f32_to_bf16(v0.w);
    r[4] = (short)f32_to_bf16(v1.x); r[5] = (short)f32_to_bf16(v1.y);
    r[6] = (short)f32_to_bf16(v1.z); r[7] = (short)f32_to_bf16(v1.w);
    xb[idx] = r;
  } else {
    const int gid = (bid - 16384) * 256 + threadIdx.x;   // OUT_F * IN_F / 4 threads
    const int o = gid >> 10;
    const int i = (gid & 1023) << 2;                      // 4 consecutive i, same j-block
    const int ib = o >> 10, p = o & 1023;
    const int jb = i >> 10, q = i & 1023;
    float r0 = 0.f, r1 = 0.f, r2 = 0.f, r3 = 0.f;
#pragma unroll
    for (int k = 0; k < 4; ++k) {
      float ak = a[k * 16 + ib * 4 + jb];
      const float4 sv = *(const float4*)(s + (((size_t)(k * 1024 + p)) << 10) + q);
      r0 += ak * sv.x; r1 += ak * sv.y; r2 += ak * sv.z; r3 += ak * sv.w;
    }
    ushort4 w;
    w.x = f32_to_bf16(r0); w.y = f32_to_bf16(r1);
    w.z = f32_to_bf16(r2); w.w = f32_to_bf16(r3);
    *(ushort4*)(wb + ((size_t)o << 12) + i) = w;
  }
}

// ---------------- GEMM: C[M,N] = A[M,K] @ B[N,K]^T + bias, bf16 in / f32 out ----------------
// m97 structure: 128x128 tile, 4 waves (64x64 each), BK=64, global_load_lds width 16,
// mfma_f32_16x16x32_bf16, XOR-granule swizzle (inverse-swizzled GLOBAL source, linear
// LDS dest, swizzled ds_read column) — 0 bank conflicts measured.
//
// Evidence ladder (this problem, this chip):
//   r0/r4: this kernel @ launch_bounds(256,2): 257 us, MfmaUtil 55%, Occ 37.7% (12 waves/CU)
//   r5:    2-wave 64x128/wave variant:         297 us, MfmaUtil 42%, Occ 17%   (5.4 waves/CU)
//   r2/r3: 8-wave 256^2 8-phase port:          335+ us, MfmaUtil 34%, 8 waves/CU
//   => perf tracks waves/CU (latency/barrier-drain hiding), NOT FLOP/LDS-byte.
// Occupancy math: ~60 VGPR + 64 AGPR + alignment ~= 130 regs/wave -> floor(512/130)=3
// waves/SIMD (the measured 12/CU). LDS allows 5 blocks. launch_bounds(256,4) forces the
// allocator under the 128-reg boundary -> 4 waves/SIMD = 16 waves/CU = 4 blocks/CU.
__global__ __launch_bounds__(256, 4)
void gemm_bias_kernel(const unsigned short* __restrict__ A,
                      const unsigned short* __restrict__ B,
                      const float* __restrict__ bias,
                      float* __restrict__ C) {
  __shared__ unsigned short As[BM * BK];   // 16 KB, LDS[row][gran g] = Aglob[row][gran g ^ (row&7)]
  __shared__ unsigned short Bs[BN * BK];   // 16 KB, same swizzle

  const int tid  = threadIdx.x;
  const int lane = tid & 63;
  const int wave = tid >> 6;
  const int m0 = blockIdx.y * BM;
  const int n0 = blockIdx.x * BN;
  const int wm = (wave >> 1) * 64;
  const int wn = (wave & 1) * 64;

  f32x4 acc[4][4];
#pragma unroll
  for (int mi = 0; mi < 4; ++mi)
#pragma unroll
    for (int ni = 0; ni < 4; ++ni)
      acc[mi][ni] = (f32x4){0.f, 0.f, 0.f, 0.f};

  // staging map: pass p covers rows p*32 + (tid>>3); granule (tid&7), swizzled source
  const int srow = tid >> 3;
  const int sgr  = (tid & 7) ^ (srow & 7);
  const unsigned short* Ag = A + (size_t)(m0 + srow) * GK + sgr * 8;
  const unsigned short* Bg = B + (size_t)(n0 + srow) * GK + sgr * 8;
  unsigned short* Asd = As + tid * 8;      // lane-contiguous LDS dest
  unsigned short* Bsd = Bs + tid * 8;

  const int ln15 = lane & 15;
  const int quad = lane >> 4;
  const int sw   = lane & 7;               // == (frag row) & 7
  int rowA[4], rowB[4];
#pragma unroll
  for (int t = 0; t < 4; ++t) {
    rowA[t] = (wm + t * 16 + ln15) * BK;
    rowB[t] = (wn + t * 16 + ln15) * BK;
  }

  for (int k0 = 0; k0 < GK; k0 += BK) {
#pragma unroll
    for (int p = 0; p < 4; ++p) {
      __builtin_amdgcn_global_load_lds((const gvoid*)(Ag + (size_t)(p * 32) * GK + k0),
                                       (lvoid*)(Asd + p * 2048), 16, 0, 0);
      __builtin_amdgcn_global_load_lds((const gvoid*)(Bg + (size_t)(p * 32) * GK + k0),
                                       (lvoid*)(Bsd + p * 2048), 16, 0, 0);
    }
    __syncthreads();
#pragma unroll
    for (int half = 0; half < 2; ++half) {
      const int gk   = half * 4 + quad;          // source granule wanted (k = gk*8 + j)
      const int cofs = ((gk ^ sw) << 3);         // swizzled LDS column (elements)
      bf16x8 af[4], bfr[4];
#pragma unroll
      for (int t = 0; t < 4; ++t) {
        af[t]  = *(const bf16x8*)(As + rowA[t] + cofs);
        bfr[t] = *(const bf16x8*)(Bs + rowB[t] + cofs);
      }
#pragma unroll
      for (int mi = 0; mi < 4; ++mi)
#pragma unroll
        for (int ni = 0; ni < 4; ++ni)
          acc[mi][ni] = __builtin_amdgcn_mfma_f32_16x16x32_bf16(af[mi], bfr[ni],
                                                                acc[mi][ni], 0, 0, 0);
    }
    __syncthreads();
  }

  // epilogue: C/D layout col = lane&15, row = quad*4 + reg  [m89/m91 verified]
#pragma unroll
  for (int ni = 0; ni < 4; ++ni) {
    const int col = n0 + wn + ni * 16 + ln15;
    const float bv = bias[col];
#pragma unroll
    for (int mi = 0; mi < 4; ++mi) {
      const int rowb = m0 + wm + mi * 16 + quad * 4;
#pragma unroll
      for (int r = 0; r < 4; ++r)
        C[(size_t)(rowb + r) * GN + col] = acc[mi][ni][r] + bv;
    }
  }
}

// ---------------- naive fallback (only if ws too small) ----------------
__global__ void naive_kernel(const float* __restrict__ x, const float* __restrict__ a,
                             const float* __restrict__ s, const float* __restrict__ bias,
                             float* __restrict__ out) {
  long long idx = (long long)blockIdx.x * blockDim.x + threadIdx.x;
  if (idx >= (long long)TOKENS * OUT_F) return;
  int t = (int)(idx >> 12);
  int o = (int)(idx & 4095);
  int ib = o >> 10, p = o & 1023;
  float acc = bias[o];
  for (int jb = 0; jb < 4; ++jb) {
    float a0 = a[0  + ib * 4 + jb];
    float a1 = a[16 + ib * 4 + jb];
    float a2 = a[32 + ib * 4 + jb];
    float a3 = a[48 + ib * 4 + jb];
    const float* xr = x + (size_t)t * IN_F + jb * 1024;
    const float* s0 = s + (size_t)p * 1024;
    const float* s1 = s0 + 1048576;
    const float* s2 = s1 + 1048576;
    const float* s3 = s2 + 1048576;
    for (int q = 0; q < 1024; ++q) {
      float w = a0 * s0[q] + a1 * s1[q] + a2 * s2[q] + a3 * s3[q];
      acc += xr[q] * w;
    }
  }
  out[idx] = acc;
}

extern "C" void kernel_launch(void* const* d_in, const int* in_sizes, int n_in,
                              void* d_out, int out_size, void* d_ws, size_t ws_size,
                              hipStream_t stream) {
  const float* x    = (const float*)d_in[0];
  const float* a    = (const float*)d_in[1];
  const float* s    = (const float*)d_in[2];
  const float* bias = (const float*)d_in[3];
  float* out = (float*)d_out;

  const size_t xb_elems = (size_t)TOKENS * IN_F;          // 33.5M bf16 = 67 MB
  const size_t wb_elems = (size_t)OUT_F * IN_F;           // 16.7M bf16 = 33.5 MB
  const size_t need = (xb_elems + wb_elems) * sizeof(unsigned short);

  if (ws_size >= need) {
    unsigned short* Xb = (unsigned short*)d_ws;
    unsigned short* Wb = Xb + xb_elems;
    const int cast_blocks  = (int)(xb_elems / 8 / 256);   // 16384
    const int build_blocks = (int)(wb_elems / 4 / 256);   // 16384
    prep_kernel<<<cast_blocks + build_blocks, 256, 0, stream>>>(
        (const float4*)x, (bf16x8*)Xb, a, s, Wb);
    dim3 grid(GN / BN, TOKENS / BM);                      // (32, 64) = 2048 blocks
    gemm_bias_kernel<<<grid, 256, 0, stream>>>(Xb, Wb, bias, out);
  } else {
    long long total = (long long)TOKENS * OUT_F;
    naive_kernel<<<(int)((total + 255) / 256), 256, 0, stream>>>(x, a, s, bias, out);
  }
}